// Round 7
// baseline (284.248 us; speedup 1.0000x reference)
//
#include <hip/hip_runtime.h>
#include <math.h>

#define N_NODES 50000
#define E_EDGES 800000
#define D_DIM   128
#define H_HEADS 8
#define DH_DIM  16
#define DFF     512

#define SCAN_BLOCKS 98  // 98*512 = 50176 >= N_NODES+1

typedef __bf16 bf16_t;
typedef bf16_t bf16x8 __attribute__((ext_vector_type(8)));
typedef float f32x4 __attribute__((ext_vector_type(4)));
typedef unsigned short u16x8 __attribute__((ext_vector_type(8)));

#define SWZ(r) (((r) & 7) << 4)

__device__ __forceinline__ float lrelu(float v) { return v > 0.f ? v : 0.01f * v; }
__device__ __forceinline__ float elu(float v) { return v > 0.f ? v : __expf(v) - 1.f; }
__device__ __forceinline__ unsigned short f2b(float f) {
    unsigned u = __float_as_uint(f);
    unsigned r = (u + 0x7FFFu + ((u >> 16) & 1u)) >> 16;
    return (unsigned short)r;
}

// ---------------- zero counts ----------------
__global__ void k_zero(int* __restrict__ counts) {
    int i = blockIdx.x * 256 + threadIdx.x;
    if (i < N_NODES) counts[i] = 0;
}

// ---------------- count in-degree ----------------
__global__ void k_count(const int* __restrict__ ed, int* __restrict__ counts) {
    int e = blockIdx.x * 256 + threadIdx.x;
    if (e < E_EDGES) atomicAdd(&counts[ed[e]], 1);
}

// ---------------- hierarchical scan ----------------
__global__ __launch_bounds__(512) void k_scan1(const int* __restrict__ counts,
                                               int* __restrict__ bsum) {
    int i = blockIdx.x * 512 + threadIdx.x;
    int v = (i < N_NODES) ? counts[i] : 0;
    #pragma unroll
    for (int o = 1; o < 64; o <<= 1) v += __shfl_xor(v, o);
    __shared__ int ws[8];
    if ((threadIdx.x & 63) == 0) ws[threadIdx.x >> 6] = v;
    __syncthreads();
    if (threadIdx.x == 0) {
        int s = 0;
        #pragma unroll
        for (int k = 0; k < 8; ++k) s += ws[k];
        bsum[blockIdx.x] = s;
    }
}

__global__ __launch_bounds__(128) void k_scan2(const int* __restrict__ bsum,
                                               int* __restrict__ boff) {
    __shared__ int tmp[128];
    int t = threadIdx.x;
    int v = (t < SCAN_BLOCKS) ? bsum[t] : 0;
    tmp[t] = v;
    __syncthreads();
    for (int o = 1; o < 128; o <<= 1) {
        int u = (t >= o) ? tmp[t - o] : 0;
        __syncthreads();
        tmp[t] += u;
        __syncthreads();
    }
    boff[t] = (t == 0) ? 0 : tmp[t - 1];
}

__global__ __launch_bounds__(512) void k_scan3(const int* __restrict__ counts,
                                               const int* __restrict__ boff,
                                               int* __restrict__ csr_off,
                                               int* __restrict__ cursor) {
    int t = threadIdx.x;
    int i = blockIdx.x * 512 + t;
    int v = (i < N_NODES) ? counts[i] : 0;
    int lane = t & 63, w = t >> 6;
    int xs = v;
    #pragma unroll
    for (int o = 1; o < 64; o <<= 1) {
        int u = __shfl_up(xs, o);
        if (lane >= o) xs += u;
    }
    __shared__ int ws[8];
    __shared__ int wo[8];
    if (lane == 63) ws[w] = xs;
    __syncthreads();
    if (t == 0) {
        int s = 0;
        #pragma unroll
        for (int k = 0; k < 8; ++k) { wo[k] = s; s += ws[k]; }
    }
    __syncthreads();
    int excl = xs - v + wo[w] + boff[blockIdx.x];
    if (i < N_NODES) { csr_off[i] = excl; cursor[i] = excl; }
    if (i == N_NODES) csr_off[N_NODES] = E_EDGES;
}

// ---------------- fill CSR with src ids ----------------
__global__ void k_fill(const int* __restrict__ es, const int* __restrict__ ed,
                       int* __restrict__ cursor, int* __restrict__ csr_src) {
    int e = blockIdx.x * 256 + threadIdx.x;
    if (e < E_EDGES) {
        int pos = atomicAdd(&cursor[ed[e]], 1);
        csr_src[pos] = es[e];
    }
}

// ---------------- weight prep: transpose + bf16 ----------------
// W1T[c][k] (512x128), W2T[c][k] (128x512), WpT[c][k] (128x128)
__global__ void k_prep(const float* __restrict__ W1, const float* __restrict__ W2,
                       const float* __restrict__ Wfc,
                       bf16_t* __restrict__ W1T, bf16_t* __restrict__ W2T,
                       bf16_t* __restrict__ WpT) {
    int id = blockIdx.x * 256 + threadIdx.x;
    if (id < 512 * 128) {
        int c = id >> 7, k = id & 127;
        W1T[id] = (bf16_t)W1[(size_t)k * 512 + c];
        int c2 = id >> 9, k2 = id & 511;
        W2T[id] = (bf16_t)W2[(size_t)k2 * 128 + c2];
        if (id < 128 * 128) {
            int cp = id >> 7, kp = id & 127;
            WpT[id] = (bf16_t)Wfc[(cp >> 4) * 2048 + kp * 16 + (cp & 15)];
        }
    }
}

// ---------------- z = x @ Wp via bf16 MFMA + fused el/er + zb ----------------
// 64 rows/block, 512 threads (8 waves); wave wv = head wv (cols wv*16..+16)
__global__ __launch_bounds__(512) void k_proj(const float* __restrict__ x,
                                              const bf16_t* __restrict__ WpT,
                                              const float* __restrict__ a_l,
                                              const float* __restrict__ a_r,
                                              unsigned short* __restrict__ zb,
                                              float* __restrict__ el,
                                              float* __restrict__ er) {
    __shared__ char xbA[16384];  // bf16[64][128], row stride 256B, swizzled
    int t = threadIdx.x;
    int r0 = blockIdx.x * 64;

    // phase 0: x -> bf16 LDS tile
    {
        int r = t >> 3, c0 = (t & 7) * 16;
        int gr = r0 + r;
        u16x8 pk0, pk1;
        if (gr < N_NODES) {
            #pragma unroll
            for (int q = 0; q < 2; ++q) {
                float4 a4 = *(const float4*)&x[(size_t)gr * 128 + c0 + q * 8];
                float4 b4 = *(const float4*)&x[(size_t)gr * 128 + c0 + q * 8 + 4];
                u16x8 pk;
                pk[0] = f2b(a4.x); pk[1] = f2b(a4.y); pk[2] = f2b(a4.z); pk[3] = f2b(a4.w);
                pk[4] = f2b(b4.x); pk[5] = f2b(b4.y); pk[6] = f2b(b4.z); pk[7] = f2b(b4.w);
                if (q == 0) pk0 = pk; else pk1 = pk;
            }
        } else {
            #pragma unroll
            for (int i = 0; i < 8; ++i) { pk0[i] = 0; pk1[i] = 0; }
        }
        int base = r * 256 + c0 * 2;
        *(u16x8*)(xbA + (base ^ SWZ(r))) = pk0;
        *(u16x8*)(xbA + ((base + 16) ^ SWZ(r))) = pk1;
    }
    __syncthreads();

    int wv = t >> 6, l = t & 63;
    int lr = l & 15, lg = l >> 4;

    f32x4 acc[4] = {};
    #pragma unroll
    for (int ks = 0; ks < 4; ++ks) {
        bf16x8 b = *(const bf16x8*)(WpT + (wv * 16 + lr) * 128 + ks * 32 + lg * 8);
        #pragma unroll
        for (int mi = 0; mi < 4; ++mi) {
            int row = mi * 16 + lr;
            int off = (row * 256 + ks * 64 + lg * 16) ^ SWZ(row);
            bf16x8 a = *(const bf16x8*)(xbA + off);
            acc[mi] = __builtin_amdgcn_mfma_f32_16x16x32_bf16(a, b, acc[mi], 0, 0, 0);
        }
    }

    // epilogue: zb store + in-register el/er reduction over the 16 col-lanes
    float alv = a_l[wv * 16 + lr];
    float arv = a_r[wv * 16 + lr];
    float outL = 0.f, outR = 0.f;
    #pragma unroll
    for (int mi = 0; mi < 4; ++mi) {
        #pragma unroll
        for (int rg = 0; rg < 4; ++rg) {
            int row = mi * 16 + lg * 4 + rg;
            int grr = r0 + row;
            float v = acc[mi][rg];
            if (grr < N_NODES) zb[(size_t)grr * 128 + wv * 16 + lr] = f2b(v);
            float pl = v * alv, pr = v * arv;
            pl += __shfl_xor(pl, 1); pr += __shfl_xor(pr, 1);
            pl += __shfl_xor(pl, 2); pr += __shfl_xor(pr, 2);
            pl += __shfl_xor(pl, 4); pr += __shfl_xor(pr, 4);
            pl += __shfl_xor(pl, 8); pr += __shfl_xor(pr, 8);
            if (lr == mi * 4 + rg) { outL = pl; outR = pr; }
        }
    }
    int myrow = r0 + (lr >> 2) * 16 + lg * 4 + (lr & 3);
    if (myrow < N_NODES) {
        el[myrow * 8 + wv] = outL;
        er[myrow * 8 + wv] = outR;
    }
}

// ---------------- fused per-node softmax + aggregate (wave per node) --------
__global__ __launch_bounds__(256) void k_node(const int* __restrict__ csr_off,
                                              const int* __restrict__ csr_src,
                                              const float* __restrict__ el,
                                              const float* __restrict__ er,
                                              const unsigned short* __restrict__ zb,
                                              float* __restrict__ out) {
    int n = blockIdx.x * 4 + (threadIdx.x >> 6);
    if (n >= N_NODES) return;
    int lane = threadIdx.x & 63;
    int h = lane >> 3, s = lane & 7;
    int row = csr_off[n];
    int deg = csr_off[n + 1] - row;
    if (deg == 0) {
        *(float2*)&out[(size_t)n * 128 + lane * 2] = make_float2(0.f, 0.f);
        return;
    }
    float erv = er[n * 8 + h];
    int nch = (deg + 7) >> 3;

    float ev[8];
    int srcv[8];
    float mx = -INFINITY;
    for (int c = 0; c < nch; ++c) {
        int k = c * 8 + s;
        int src = 0;
        float e = -INFINITY;
        if (k < deg) {
            src = csr_src[row + k];
            e = lrelu(el[src * 8 + h] + erv);
        }
        if (c < 8) { ev[c] = e; srcv[c] = src; }
        mx = fmaxf(mx, e);
    }
    mx = fmaxf(mx, __shfl_xor(mx, 1));
    mx = fmaxf(mx, __shfl_xor(mx, 2));
    mx = fmaxf(mx, __shfl_xor(mx, 4));

    float ps = 0.f;
    float2 acc = make_float2(0.f, 0.f);
    int hj = lane >> 3;
    const unsigned short* zbl = zb + lane * 2;
    for (int c = 0; c < nch; ++c) {
        float e;
        int src;
        if (c < 8) {
            e = ev[c]; src = srcv[c];
        } else {
            int k = c * 8 + s;
            src = 0; e = -INFINITY;
            if (k < deg) {
                src = csr_src[row + k];
                e = lrelu(el[src * 8 + h] + erv);
            }
        }
        float p = ((c * 8 + s) < deg) ? __expf(e - mx) : 0.f;
        ps += p;
        float a[8];
        int se[8];
        #pragma unroll
        for (int tt = 0; tt < 8; ++tt) {
            a[tt] = __shfl(p, hj * 8 + tt);
            se[tt] = __shfl(src, tt);
        }
        unsigned u[8];
        #pragma unroll
        for (int tt = 0; tt < 8; ++tt)
            u[tt] = *(const unsigned*)(zbl + (size_t)se[tt] * 128);
        #pragma unroll
        for (int tt = 0; tt < 8; ++tt) {
            acc.x += a[tt] * __uint_as_float(u[tt] << 16);
            acc.y += a[tt] * __uint_as_float(u[tt] & 0xFFFF0000u);
        }
    }
    ps += __shfl_xor(ps, 1);
    ps += __shfl_xor(ps, 2);
    ps += __shfl_xor(ps, 4);
    float sumh = __shfl(ps, hj * 8);
    float inv = 1.f / fmaxf(sumh, 1e-9f);
    *(float2*)&out[(size_t)n * 128 + lane * 2] = make_float2(acc.x * inv, acc.y * inv);
}

// ---------------- fused elu+residual+LN+FFN with bf16 MFMA ----------------
// Two 256-f passes over a 32KB inA. LDS total 48KB -> 3 blocks/CU.
__global__ __launch_bounds__(512, 6) void k_ffn(const float* __restrict__ x,
                                                const float* __restrict__ gamma,
                                                const float* __restrict__ beta,
                                                const bf16_t* __restrict__ W1T,
                                                const float* __restrict__ b1,
                                                const bf16_t* __restrict__ W2T,
                                                const float* __restrict__ b2,
                                                float* __restrict__ out) {
    __shared__ char smem[49152];
    char* lnA = smem;           // bf16[64][128], row stride 256B, swizzled
    char* inA = smem + 16384;   // bf16[64][256], row stride 512B, swizzled
    int t = threadIdx.x;
    int r0 = blockIdx.x * 64;

    // phase 0: h = x + elu(gat); LN in registers; ln -> lnA (bf16, swizzled)
    {
        int r = t >> 3, c0 = (t & 7) * 16;
        int gr = r0 + r;
        float hv[16];
        if (gr < N_NODES) {
            #pragma unroll
            for (int q = 0; q < 4; ++q) {
                float4 g4 = *(const float4*)&out[(size_t)gr * 128 + c0 + q * 4];
                float4 x4 = *(const float4*)&x[(size_t)gr * 128 + c0 + q * 4];
                float ga[4] = {g4.x, g4.y, g4.z, g4.w};
                float xa[4] = {x4.x, x4.y, x4.z, x4.w};
                #pragma unroll
                for (int i = 0; i < 4; ++i) hv[q * 4 + i] = xa[i] + elu(ga[i]);
            }
        } else {
            #pragma unroll
            for (int i = 0; i < 16; ++i) hv[i] = 0.f;
        }
        float sm = 0.f, sq = 0.f;
        #pragma unroll
        for (int i = 0; i < 16; ++i) { sm += hv[i]; sq += hv[i] * hv[i]; }
        sm += __shfl_xor(sm, 1); sq += __shfl_xor(sq, 1);
        sm += __shfl_xor(sm, 2); sq += __shfl_xor(sq, 2);
        sm += __shfl_xor(sm, 4); sq += __shfl_xor(sq, 4);
        float mu = sm * (1.f / 128.f);
        float rs = rsqrtf(sq * (1.f / 128.f) - mu * mu + 1e-5f);
        u16x8 pk0, pk1;
        #pragma unroll
        for (int i = 0; i < 8; ++i) {
            pk0[i] = f2b((hv[i] - mu) * rs * gamma[c0 + i] + beta[c0 + i]);
            pk1[i] = f2b((hv[8 + i] - mu) * rs * gamma[c0 + 8 + i] + beta[c0 + 8 + i]);
        }
        int base = r * 256 + c0 * 2;
        *(u16x8*)(lnA + (base ^ SWZ(r))) = pk0;
        *(u16x8*)(lnA + ((base + 16) ^ SWZ(r))) = pk1;
    }
    __syncthreads();

    int wv = t >> 6, l = t & 63;
    int lr = l & 15, lg = l >> 4;

    f32x4 acc2[4] = {};
    #pragma unroll
    for (int p = 0; p < 2; ++p) {
        int F0 = p * 256;
        // GEMM1 partial: inter[:, F0..F0+256); wave covers 32 cols
        {
            f32x4 acc[4][2] = {};
            #pragma unroll
            for (int ks = 0; ks < 4; ++ks) {
                bf16x8 a[4], b[2];
                #pragma unroll
                for (int mi = 0; mi < 4; ++mi) {
                    int row = mi * 16 + lr;
                    int off = (row * 256 + ks * 64 + lg * 16) ^ SWZ(row);
                    a[mi] = *(const bf16x8*)(lnA + off);
                }
                #pragma unroll
                for (int ni = 0; ni < 2; ++ni) {
                    int c = F0 + wv * 32 + ni * 16 + lr;
                    b[ni] = *(const bf16x8*)(W1T + (size_t)c * 128 + ks * 32 + lg * 8);
                }
                #pragma unroll
                for (int mi = 0; mi < 4; ++mi)
                    #pragma unroll
                    for (int ni = 0; ni < 2; ++ni)
                        acc[mi][ni] = __builtin_amdgcn_mfma_f32_16x16x32_bf16(
                            a[mi], b[ni], acc[mi][ni], 0, 0, 0);
            }
            #pragma unroll
            for (int ni = 0; ni < 2; ++ni) {
                int crel = wv * 32 + ni * 16 + lr;
                float bb = b1[F0 + crel];
                #pragma unroll
                for (int mi = 0; mi < 4; ++mi) {
                    #pragma unroll
                    for (int rg = 0; rg < 4; ++rg) {
                        int row = mi * 16 + lg * 4 + rg;
                        float v = acc[mi][ni][rg] + bb;
                        v = v > 0.f ? v : 0.f;
                        *(unsigned short*)(inA + ((row * 512 + crel * 2) ^ SWZ(row))) = f2b(v);
                    }
                }
            }
        }
        __syncthreads();
        // GEMM2 partial: accumulate over f in [F0, F0+256)
        {
            int n2 = wv * 16;
            #pragma unroll
            for (int ks = 0; ks < 8; ++ks) {
                bf16x8 bfr = *(const bf16x8*)(W2T + (size_t)(n2 + lr) * 512 + F0 + ks * 32 + lg * 8);
                #pragma unroll
                for (int mi = 0; mi < 4; ++mi) {
                    int row = mi * 16 + lr;
                    int off = (row * 512 + ks * 64 + lg * 16) ^ SWZ(row);
                    bf16x8 a2 = *(const bf16x8*)(inA + off);
                    acc2[mi] = __builtin_amdgcn_mfma_f32_16x16x32_bf16(a2, bfr, acc2[mi], 0, 0, 0);
                }
            }
        }
        if (p == 0) __syncthreads();
    }

    // epilogue
    {
        int n2 = wv * 16;
        float bb2 = b2[n2 + lr];
        #pragma unroll
        for (int mi = 0; mi < 4; ++mi) {
            #pragma unroll
            for (int rg = 0; rg < 4; ++rg) {
                int row = mi * 16 + lg * 4 + rg;
                int gr = r0 + row;
                if (gr < N_NODES) {
                    size_t idx = (size_t)gr * 128 + n2 + lr;
                    float g = out[idx];
                    out[idx] = acc2[mi][rg] + bb2 + x[idx] + elu(g);
                }
            }
        }
    }
}

extern "C" void kernel_launch(void* const* d_in, const int* in_sizes, int n_in,
                              void* d_out, int out_size, void* d_ws, size_t ws_size,
                              hipStream_t stream) {
    const float* x     = (const float*)d_in[0];
    const float* Wfc   = (const float*)d_in[1];
    const float* a_l   = (const float*)d_in[2];
    const float* a_r   = (const float*)d_in[3];
    const float* gamma = (const float*)d_in[4];
    const float* beta  = (const float*)d_in[5];
    const float* W1    = (const float*)d_in[6];
    const float* b1    = (const float*)d_in[7];
    const float* W2    = (const float*)d_in[8];
    const float* b2    = (const float*)d_in[9];
    const int*   es    = (const int*)d_in[10];
    const int*   ed    = (const int*)d_in[11];
    float* out = (float*)d_out;

    bf16_t* W1T = (bf16_t*)d_ws;                      // 512*128
    bf16_t* W2T = W1T + 512 * 128;                    // 128*512
    bf16_t* WpT = W2T + 128 * 512;                    // 128*128
    unsigned short* zb = (unsigned short*)(WpT + 128 * 128);  // N*128 bf16
    float* el = (float*)(zb + (size_t)N_NODES * 128); // N*8
    float* er = el + N_NODES * 8;                     // N*8
    int* counts  = (int*)(er + N_NODES * 8);          // N
    int* csr_off = counts + N_NODES;                  // N+1
    int* cursor  = csr_off + N_NODES + 1;             // N+1
    int* csr_src = cursor + N_NODES + 1;              // E
    int* bsum    = csr_src + E_EDGES;                 // SCAN_BLOCKS
    int* boff    = bsum + 128;                        // 128

    k_zero<<<dim3((N_NODES + 255) / 256), dim3(256), 0, stream>>>(counts);
    k_count<<<dim3((E_EDGES + 255) / 256), dim3(256), 0, stream>>>(ed, counts);
    k_scan1<<<dim3(SCAN_BLOCKS), dim3(512), 0, stream>>>(counts, bsum);
    k_scan2<<<dim3(1), dim3(128), 0, stream>>>(bsum, boff);
    k_scan3<<<dim3(SCAN_BLOCKS), dim3(512), 0, stream>>>(counts, boff, csr_off, cursor);
    k_fill<<<dim3((E_EDGES + 255) / 256), dim3(256), 0, stream>>>(es, ed, cursor, csr_src);
    k_prep<<<dim3(256), dim3(256), 0, stream>>>(W1, W2, Wfc, W1T, W2T, WpT);
    k_proj<<<dim3((N_NODES + 63) / 64), dim3(512), 0, stream>>>(x, WpT, a_l, a_r, zb, el, er);
    k_node<<<dim3((N_NODES + 3) / 4), dim3(256), 0, stream>>>(csr_off, csr_src, el, er, zb, out);
    k_ffn<<<dim3((N_NODES + 63) / 64), dim3(512), 0, stream>>>(x, gamma, beta, W1T, b1, W2T, b2, out);
}

// Round 8
// 239.899 us; speedup vs baseline: 1.1849x; 1.1849x over previous
//
#include <hip/hip_runtime.h>
#include <math.h>

#define N_NODES 50000
#define E_EDGES 800000
#define D_DIM   128
#define H_HEADS 8
#define DH_DIM  16
#define DFF     512

#define SCAN_BLOCKS 98  // 98*512 = 50176 >= N_NODES+1

typedef __bf16 bf16_t;
typedef bf16_t bf16x8 __attribute__((ext_vector_type(8)));
typedef float f32x4 __attribute__((ext_vector_type(4)));
typedef unsigned short u16x8 __attribute__((ext_vector_type(8)));

#define SWZ(r) (((r) & 7) << 4)

__device__ __forceinline__ float lrelu(float v) { return v > 0.f ? v : 0.01f * v; }
__device__ __forceinline__ float elu(float v) { return v > 0.f ? v : __expf(v) - 1.f; }
__device__ __forceinline__ unsigned short f2b(float f) {
    unsigned u = __float_as_uint(f);
    unsigned r = (u + 0x7FFFu + ((u >> 16) & 1u)) >> 16;
    return (unsigned short)r;
}

// ---------------- zero counts ----------------
__global__ void k_zero(int* __restrict__ counts) {
    int i = blockIdx.x * 256 + threadIdx.x;
    if (i < N_NODES) counts[i] = 0;
}

// ---------------- count in-degree ----------------
__global__ void k_count(const int* __restrict__ ed, int* __restrict__ counts) {
    int e = blockIdx.x * 256 + threadIdx.x;
    if (e < E_EDGES) atomicAdd(&counts[ed[e]], 1);
}

// ---------------- hierarchical scan ----------------
__global__ __launch_bounds__(512) void k_scan1(const int* __restrict__ counts,
                                               int* __restrict__ bsum) {
    int i = blockIdx.x * 512 + threadIdx.x;
    int v = (i < N_NODES) ? counts[i] : 0;
    #pragma unroll
    for (int o = 1; o < 64; o <<= 1) v += __shfl_xor(v, o);
    __shared__ int ws[8];
    if ((threadIdx.x & 63) == 0) ws[threadIdx.x >> 6] = v;
    __syncthreads();
    if (threadIdx.x == 0) {
        int s = 0;
        #pragma unroll
        for (int k = 0; k < 8; ++k) s += ws[k];
        bsum[blockIdx.x] = s;
    }
}

__global__ __launch_bounds__(128) void k_scan2(const int* __restrict__ bsum,
                                               int* __restrict__ boff) {
    __shared__ int tmp[128];
    int t = threadIdx.x;
    int v = (t < SCAN_BLOCKS) ? bsum[t] : 0;
    tmp[t] = v;
    __syncthreads();
    for (int o = 1; o < 128; o <<= 1) {
        int u = (t >= o) ? tmp[t - o] : 0;
        __syncthreads();
        tmp[t] += u;
        __syncthreads();
    }
    boff[t] = (t == 0) ? 0 : tmp[t - 1];
}

__global__ __launch_bounds__(512) void k_scan3(const int* __restrict__ counts,
                                               const int* __restrict__ boff,
                                               int* __restrict__ csr_off,
                                               int* __restrict__ cursor) {
    int t = threadIdx.x;
    int i = blockIdx.x * 512 + t;
    int v = (i < N_NODES) ? counts[i] : 0;
    int lane = t & 63, w = t >> 6;
    int xs = v;
    #pragma unroll
    for (int o = 1; o < 64; o <<= 1) {
        int u = __shfl_up(xs, o);
        if (lane >= o) xs += u;
    }
    __shared__ int ws[8];
    __shared__ int wo[8];
    if (lane == 63) ws[w] = xs;
    __syncthreads();
    if (t == 0) {
        int s = 0;
        #pragma unroll
        for (int k = 0; k < 8; ++k) { wo[k] = s; s += ws[k]; }
    }
    __syncthreads();
    int excl = xs - v + wo[w] + boff[blockIdx.x];
    if (i < N_NODES) { csr_off[i] = excl; cursor[i] = excl; }
    if (i == N_NODES) csr_off[N_NODES] = E_EDGES;
}

// ---------------- fill CSR with src ids ----------------
__global__ void k_fill(const int* __restrict__ es, const int* __restrict__ ed,
                       int* __restrict__ cursor, int* __restrict__ csr_src) {
    int e = blockIdx.x * 256 + threadIdx.x;
    if (e < E_EDGES) {
        int pos = atomicAdd(&cursor[ed[e]], 1);
        csr_src[pos] = es[e];
    }
}

// ---------------- weight prep: transpose + bf16 ----------------
__global__ void k_prep(const float* __restrict__ W1, const float* __restrict__ W2,
                       const float* __restrict__ Wfc,
                       bf16_t* __restrict__ W1T, bf16_t* __restrict__ W2T,
                       bf16_t* __restrict__ WpT) {
    int id = blockIdx.x * 256 + threadIdx.x;
    if (id < 512 * 128) {
        int c = id >> 7, k = id & 127;
        W1T[id] = (bf16_t)W1[(size_t)k * 512 + c];
        int c2 = id >> 9, k2 = id & 511;
        W2T[id] = (bf16_t)W2[(size_t)k2 * 128 + c2];
        if (id < 128 * 128) {
            int cp = id >> 7, kp = id & 127;
            WpT[id] = (bf16_t)Wfc[(cp >> 4) * 2048 + kp * 16 + (cp & 15)];
        }
    }
}

// ---------------- z = x @ Wp via bf16 MFMA + fused el/er + zb ----------------
__global__ __launch_bounds__(512) void k_proj(const float* __restrict__ x,
                                              const bf16_t* __restrict__ WpT,
                                              const float* __restrict__ a_l,
                                              const float* __restrict__ a_r,
                                              unsigned short* __restrict__ zb,
                                              float* __restrict__ el,
                                              float* __restrict__ er) {
    __shared__ char xbA[16384];  // bf16[64][128], row stride 256B, swizzled
    int t = threadIdx.x;
    int r0 = blockIdx.x * 64;

    {
        int r = t >> 3, c0 = (t & 7) * 16;
        int gr = r0 + r;
        u16x8 pk0, pk1;
        if (gr < N_NODES) {
            #pragma unroll
            for (int q = 0; q < 2; ++q) {
                float4 a4 = *(const float4*)&x[(size_t)gr * 128 + c0 + q * 8];
                float4 b4 = *(const float4*)&x[(size_t)gr * 128 + c0 + q * 8 + 4];
                u16x8 pk;
                pk[0] = f2b(a4.x); pk[1] = f2b(a4.y); pk[2] = f2b(a4.z); pk[3] = f2b(a4.w);
                pk[4] = f2b(b4.x); pk[5] = f2b(b4.y); pk[6] = f2b(b4.z); pk[7] = f2b(b4.w);
                if (q == 0) pk0 = pk; else pk1 = pk;
            }
        } else {
            #pragma unroll
            for (int i = 0; i < 8; ++i) { pk0[i] = 0; pk1[i] = 0; }
        }
        int base = r * 256 + c0 * 2;
        *(u16x8*)(xbA + (base ^ SWZ(r))) = pk0;
        *(u16x8*)(xbA + ((base + 16) ^ SWZ(r))) = pk1;
    }
    __syncthreads();

    int wv = t >> 6, l = t & 63;
    int lr = l & 15, lg = l >> 4;

    f32x4 acc[4] = {};
    #pragma unroll
    for (int ks = 0; ks < 4; ++ks) {
        bf16x8 b = *(const bf16x8*)(WpT + (wv * 16 + lr) * 128 + ks * 32 + lg * 8);
        #pragma unroll
        for (int mi = 0; mi < 4; ++mi) {
            int row = mi * 16 + lr;
            int off = (row * 256 + ks * 64 + lg * 16) ^ SWZ(row);
            bf16x8 a = *(const bf16x8*)(xbA + off);
            acc[mi] = __builtin_amdgcn_mfma_f32_16x16x32_bf16(a, b, acc[mi], 0, 0, 0);
        }
    }

    float alv = a_l[wv * 16 + lr];
    float arv = a_r[wv * 16 + lr];
    float outL = 0.f, outR = 0.f;
    #pragma unroll
    for (int mi = 0; mi < 4; ++mi) {
        #pragma unroll
        for (int rg = 0; rg < 4; ++rg) {
            int row = mi * 16 + lg * 4 + rg;
            int grr = r0 + row;
            float v = acc[mi][rg];
            if (grr < N_NODES) zb[(size_t)grr * 128 + wv * 16 + lr] = f2b(v);
            float pl = v * alv, pr = v * arv;
            pl += __shfl_xor(pl, 1); pr += __shfl_xor(pr, 1);
            pl += __shfl_xor(pl, 2); pr += __shfl_xor(pr, 2);
            pl += __shfl_xor(pl, 4); pr += __shfl_xor(pr, 4);
            pl += __shfl_xor(pl, 8); pr += __shfl_xor(pr, 8);
            if (lr == mi * 4 + rg) { outL = pl; outR = pr; }
        }
    }
    int myrow = r0 + (lr >> 2) * 16 + lg * 4 + (lr & 3);
    if (myrow < N_NODES) {
        el[myrow * 8 + wv] = outL;
        er[myrow * 8 + wv] = outR;
    }
}

// ---------------- fused per-node softmax + aggregate (wave per node) --------
// Static-unrolled 8-chunk loops -> ev/srcv live in VGPRs (no scratch).
__global__ __launch_bounds__(256) void k_node(const int* __restrict__ csr_off,
                                              const int* __restrict__ csr_src,
                                              const float* __restrict__ el,
                                              const float* __restrict__ er,
                                              const unsigned short* __restrict__ zb,
                                              float* __restrict__ out) {
    int n = blockIdx.x * 4 + (threadIdx.x >> 6);
    if (n >= N_NODES) return;
    int lane = threadIdx.x & 63;
    int h = lane >> 3, s = lane & 7;
    int row = csr_off[n];
    int deg = csr_off[n + 1] - row;
    if (deg == 0) {
        *(float2*)&out[(size_t)n * 128 + lane * 2] = make_float2(0.f, 0.f);
        return;
    }
    float erv = er[n * 8 + h];
    int nch = (deg + 7) >> 3;

    // pass 1: static 8 chunks in registers + running max
    float ev[8];
    int srcv[8];
    float mx = -INFINITY;
    #pragma unroll
    for (int c = 0; c < 8; ++c) {
        int k = c * 8 + s;
        int src = 0;
        float e = -INFINITY;
        if (c * 8 < deg) {  // uniform across wave
            if (k < deg) {
                src = csr_src[row + k];
                e = lrelu(el[src * 8 + h] + erv);
            }
        }
        ev[c] = e;
        srcv[c] = src;
        mx = fmaxf(mx, e);
    }
    for (int c = 8; c < nch; ++c) {  // rare: deg > 64
        int k = c * 8 + s;
        if (k < deg) {
            int src = csr_src[row + k];
            mx = fmaxf(mx, lrelu(el[src * 8 + h] + erv));
        }
    }
    mx = fmaxf(mx, __shfl_xor(mx, 1));
    mx = fmaxf(mx, __shfl_xor(mx, 2));
    mx = fmaxf(mx, __shfl_xor(mx, 4));

    // pass 2: exp + sum + gather-aggregate, static chunks
    float ps = 0.f;
    float2 acc = make_float2(0.f, 0.f);
    const unsigned short* zbl = zb + lane * 2;
    #pragma unroll
    for (int c = 0; c < 8; ++c) {
        if (c * 8 < deg) {  // uniform
            float p = ((c * 8 + s) < deg) ? __expf(ev[c] - mx) : 0.f;
            ps += p;
            float a[8];
            int se[8];
            #pragma unroll
            for (int tt = 0; tt < 8; ++tt) {
                a[tt] = __shfl(p, h * 8 + tt);
                se[tt] = __shfl(srcv[c], h * 8 + tt);
            }
            unsigned u[8];
            #pragma unroll
            for (int tt = 0; tt < 8; ++tt)
                u[tt] = *(const unsigned*)(zbl + (size_t)se[tt] * 128);
            #pragma unroll
            for (int tt = 0; tt < 8; ++tt) {
                acc.x += a[tt] * __uint_as_float(u[tt] << 16);
                acc.y += a[tt] * __uint_as_float(u[tt] & 0xFFFF0000u);
            }
        }
    }
    for (int c = 8; c < nch; ++c) {  // rare: deg > 64
        int k = c * 8 + s;
        int src = 0;
        float e = -INFINITY;
        if (k < deg) {
            src = csr_src[row + k];
            e = lrelu(el[src * 8 + h] + erv);
        }
        float p = (k < deg) ? __expf(e - mx) : 0.f;
        ps += p;
        float a[8];
        int se[8];
        #pragma unroll
        for (int tt = 0; tt < 8; ++tt) {
            a[tt] = __shfl(p, h * 8 + tt);
            se[tt] = __shfl(src, h * 8 + tt);
        }
        unsigned u[8];
        #pragma unroll
        for (int tt = 0; tt < 8; ++tt)
            u[tt] = *(const unsigned*)(zbl + (size_t)se[tt] * 128);
        #pragma unroll
        for (int tt = 0; tt < 8; ++tt) {
            acc.x += a[tt] * __uint_as_float(u[tt] << 16);
            acc.y += a[tt] * __uint_as_float(u[tt] & 0xFFFF0000u);
        }
    }
    ps += __shfl_xor(ps, 1);
    ps += __shfl_xor(ps, 2);
    ps += __shfl_xor(ps, 4);
    float sumh = __shfl(ps, h * 8);
    float inv = 1.f / fmaxf(sumh, 1e-9f);
    *(float2*)&out[(size_t)n * 128 + lane * 2] = make_float2(acc.x * inv, acc.y * inv);
}

// ---------------- fused elu+residual+LN+FFN with bf16 MFMA ----------------
// Two 256-f passes over a 32KB inA. LDS total 48KB. launch_bounds (512,4):
// cap 128 VGPR -> no spill (the (512,6) variant spilled: 186MB scratch writes).
__global__ __launch_bounds__(512, 4) void k_ffn(const float* __restrict__ x,
                                                const float* __restrict__ gamma,
                                                const float* __restrict__ beta,
                                                const bf16_t* __restrict__ W1T,
                                                const float* __restrict__ b1,
                                                const bf16_t* __restrict__ W2T,
                                                const float* __restrict__ b2,
                                                float* __restrict__ out) {
    __shared__ char smem[49152];
    char* lnA = smem;           // bf16[64][128], row stride 256B, swizzled
    char* inA = smem + 16384;   // bf16[64][256], row stride 512B, swizzled
    int t = threadIdx.x;
    int r0 = blockIdx.x * 64;

    {
        int r = t >> 3, c0 = (t & 7) * 16;
        int gr = r0 + r;
        float hv[16];
        if (gr < N_NODES) {
            #pragma unroll
            for (int q = 0; q < 4; ++q) {
                float4 g4 = *(const float4*)&out[(size_t)gr * 128 + c0 + q * 4];
                float4 x4 = *(const float4*)&x[(size_t)gr * 128 + c0 + q * 4];
                float ga[4] = {g4.x, g4.y, g4.z, g4.w};
                float xa[4] = {x4.x, x4.y, x4.z, x4.w};
                #pragma unroll
                for (int i = 0; i < 4; ++i) hv[q * 4 + i] = xa[i] + elu(ga[i]);
            }
        } else {
            #pragma unroll
            for (int i = 0; i < 16; ++i) hv[i] = 0.f;
        }
        float sm = 0.f, sq = 0.f;
        #pragma unroll
        for (int i = 0; i < 16; ++i) { sm += hv[i]; sq += hv[i] * hv[i]; }
        sm += __shfl_xor(sm, 1); sq += __shfl_xor(sq, 1);
        sm += __shfl_xor(sm, 2); sq += __shfl_xor(sq, 2);
        sm += __shfl_xor(sm, 4); sq += __shfl_xor(sq, 4);
        float mu = sm * (1.f / 128.f);
        float rs = rsqrtf(sq * (1.f / 128.f) - mu * mu + 1e-5f);
        u16x8 pk0, pk1;
        #pragma unroll
        for (int i = 0; i < 8; ++i) {
            pk0[i] = f2b((hv[i] - mu) * rs * gamma[c0 + i] + beta[c0 + i]);
            pk1[i] = f2b((hv[8 + i] - mu) * rs * gamma[c0 + 8 + i] + beta[c0 + 8 + i]);
        }
        int base = r * 256 + c0 * 2;
        *(u16x8*)(lnA + (base ^ SWZ(r))) = pk0;
        *(u16x8*)(lnA + ((base + 16) ^ SWZ(r))) = pk1;
    }
    __syncthreads();

    int wv = t >> 6, l = t & 63;
    int lr = l & 15, lg = l >> 4;

    f32x4 acc2[4] = {};
    #pragma unroll
    for (int p = 0; p < 2; ++p) {
        int F0 = p * 256;
        {
            f32x4 acc[4][2] = {};
            #pragma unroll
            for (int ks = 0; ks < 4; ++ks) {
                bf16x8 a[4], b[2];
                #pragma unroll
                for (int mi = 0; mi < 4; ++mi) {
                    int row = mi * 16 + lr;
                    int off = (row * 256 + ks * 64 + lg * 16) ^ SWZ(row);
                    a[mi] = *(const bf16x8*)(lnA + off);
                }
                #pragma unroll
                for (int ni = 0; ni < 2; ++ni) {
                    int c = F0 + wv * 32 + ni * 16 + lr;
                    b[ni] = *(const bf16x8*)(W1T + (size_t)c * 128 + ks * 32 + lg * 8);
                }
                #pragma unroll
                for (int mi = 0; mi < 4; ++mi)
                    #pragma unroll
                    for (int ni = 0; ni < 2; ++ni)
                        acc[mi][ni] = __builtin_amdgcn_mfma_f32_16x16x32_bf16(
                            a[mi], b[ni], acc[mi][ni], 0, 0, 0);
            }
            #pragma unroll
            for (int ni = 0; ni < 2; ++ni) {
                int crel = wv * 32 + ni * 16 + lr;
                float bb = b1[F0 + crel];
                #pragma unroll
                for (int mi = 0; mi < 4; ++mi) {
                    #pragma unroll
                    for (int rg = 0; rg < 4; ++rg) {
                        int row = mi * 16 + lg * 4 + rg;
                        float v = acc[mi][ni][rg] + bb;
                        v = v > 0.f ? v : 0.f;
                        *(unsigned short*)(inA + ((row * 512 + crel * 2) ^ SWZ(row))) = f2b(v);
                    }
                }
            }
        }
        __syncthreads();
        {
            int n2 = wv * 16;
            #pragma unroll
            for (int ks = 0; ks < 8; ++ks) {
                bf16x8 bfr = *(const bf16x8*)(W2T + (size_t)(n2 + lr) * 512 + F0 + ks * 32 + lg * 8);
                #pragma unroll
                for (int mi = 0; mi < 4; ++mi) {
                    int row = mi * 16 + lr;
                    int off = (row * 512 + ks * 64 + lg * 16) ^ SWZ(row);
                    bf16x8 a2 = *(const bf16x8*)(inA + off);
                    acc2[mi] = __builtin_amdgcn_mfma_f32_16x16x32_bf16(a2, bfr, acc2[mi], 0, 0, 0);
                }
            }
        }
        if (p == 0) __syncthreads();
    }

    {
        int n2 = wv * 16;
        float bb2 = b2[n2 + lr];
        #pragma unroll
        for (int mi = 0; mi < 4; ++mi) {
            #pragma unroll
            for (int rg = 0; rg < 4; ++rg) {
                int row = mi * 16 + lg * 4 + rg;
                int gr = r0 + row;
                if (gr < N_NODES) {
                    size_t idx = (size_t)gr * 128 + n2 + lr;
                    float g = out[idx];
                    out[idx] = acc2[mi][rg] + bb2 + x[idx] + elu(g);
                }
            }
        }
    }
}

extern "C" void kernel_launch(void* const* d_in, const int* in_sizes, int n_in,
                              void* d_out, int out_size, void* d_ws, size_t ws_size,
                              hipStream_t stream) {
    const float* x     = (const float*)d_in[0];
    const float* Wfc   = (const float*)d_in[1];
    const float* a_l   = (const float*)d_in[2];
    const float* a_r   = (const float*)d_in[3];
    const float* gamma = (const float*)d_in[4];
    const float* beta  = (const float*)d_in[5];
    const float* W1    = (const float*)d_in[6];
    const float* b1    = (const float*)d_in[7];
    const float* W2    = (const float*)d_in[8];
    const float* b2    = (const float*)d_in[9];
    const int*   es    = (const int*)d_in[10];
    const int*   ed    = (const int*)d_in[11];
    float* out = (float*)d_out;

    bf16_t* W1T = (bf16_t*)d_ws;                      // 512*128
    bf16_t* W2T = W1T + 512 * 128;                    // 128*512
    bf16_t* WpT = W2T + 128 * 512;                    // 128*128
    unsigned short* zb = (unsigned short*)(WpT + 128 * 128);  // N*128 bf16
    float* el = (float*)(zb + (size_t)N_NODES * 128); // N*8
    float* er = el + N_NODES * 8;                     // N*8
    int* counts  = (int*)(er + N_NODES * 8);          // N
    int* csr_off = counts + N_NODES;                  // N+1
    int* cursor  = csr_off + N_NODES + 1;             // N+1
    int* csr_src = cursor + N_NODES + 1;              // E
    int* bsum    = csr_src + E_EDGES;                 // SCAN_BLOCKS
    int* boff    = bsum + 128;                        // 128

    k_zero<<<dim3((N_NODES + 255) / 256), dim3(256), 0, stream>>>(counts);
    k_count<<<dim3((E_EDGES + 255) / 256), dim3(256), 0, stream>>>(ed, counts);
    k_scan1<<<dim3(SCAN_BLOCKS), dim3(512), 0, stream>>>(counts, bsum);
    k_scan2<<<dim3(1), dim3(128), 0, stream>>>(bsum, boff);
    k_scan3<<<dim3(SCAN_BLOCKS), dim3(512), 0, stream>>>(counts, boff, csr_off, cursor);
    k_fill<<<dim3((E_EDGES + 255) / 256), dim3(256), 0, stream>>>(es, ed, cursor, csr_src);
    k_prep<<<dim3(256), dim3(256), 0, stream>>>(W1, W2, Wfc, W1T, W2T, WpT);
    k_proj<<<dim3((N_NODES + 63) / 64), dim3(512), 0, stream>>>(x, WpT, a_l, a_r, zb, el, er);
    k_node<<<dim3((N_NODES + 3) / 4), dim3(256), 0, stream>>>(csr_off, csr_src, el, er, zb, out);
    k_ffn<<<dim3((N_NODES + 63) / 64), dim3(512), 0, stream>>>(x, gamma, beta, W1T, b1, W2T, b2, out);
}

// Round 9
// 234.395 us; speedup vs baseline: 1.2127x; 1.0235x over previous
//
#include <hip/hip_runtime.h>
#include <math.h>

#define N_NODES 50000
#define E_EDGES 800000
#define D_DIM   128
#define H_HEADS 8
#define DH_DIM  16
#define DFF     512

#define SCAN_BLOCKS 98  // 98*512 = 50176 >= N_NODES+1

typedef __bf16 bf16_t;
typedef bf16_t bf16x8 __attribute__((ext_vector_type(8)));
typedef float f32x4 __attribute__((ext_vector_type(4)));
typedef unsigned short u16x8 __attribute__((ext_vector_type(8)));

#define SWZ(r) (((r) & 7) << 4)

__device__ __forceinline__ float lrelu(float v) { return v > 0.f ? v : 0.01f * v; }
__device__ __forceinline__ float elu(float v) { return v > 0.f ? v : __expf(v) - 1.f; }
__device__ __forceinline__ unsigned short f2b(float f) {
    unsigned u = __float_as_uint(f);
    unsigned r = (u + 0x7FFFu + ((u >> 16) & 1u)) >> 16;
    return (unsigned short)r;
}

// ---------------- zero counts ----------------
__global__ void k_zero(int* __restrict__ counts) {
    int i = blockIdx.x * 256 + threadIdx.x;
    if (i < N_NODES) counts[i] = 0;
}

// ---------------- count in-degree ----------------
__global__ void k_count(const int* __restrict__ ed, int* __restrict__ counts) {
    int e = blockIdx.x * 256 + threadIdx.x;
    if (e < E_EDGES) atomicAdd(&counts[ed[e]], 1);
}

// ---------------- hierarchical scan ----------------
__global__ __launch_bounds__(512) void k_scan1(const int* __restrict__ counts,
                                               int* __restrict__ bsum) {
    int i = blockIdx.x * 512 + threadIdx.x;
    int v = (i < N_NODES) ? counts[i] : 0;
    #pragma unroll
    for (int o = 1; o < 64; o <<= 1) v += __shfl_xor(v, o);
    __shared__ int ws[8];
    if ((threadIdx.x & 63) == 0) ws[threadIdx.x >> 6] = v;
    __syncthreads();
    if (threadIdx.x == 0) {
        int s = 0;
        #pragma unroll
        for (int k = 0; k < 8; ++k) s += ws[k];
        bsum[blockIdx.x] = s;
    }
}

__global__ __launch_bounds__(128) void k_scan2(const int* __restrict__ bsum,
                                               int* __restrict__ boff) {
    __shared__ int tmp[128];
    int t = threadIdx.x;
    int v = (t < SCAN_BLOCKS) ? bsum[t] : 0;
    tmp[t] = v;
    __syncthreads();
    for (int o = 1; o < 128; o <<= 1) {
        int u = (t >= o) ? tmp[t - o] : 0;
        __syncthreads();
        tmp[t] += u;
        __syncthreads();
    }
    boff[t] = (t == 0) ? 0 : tmp[t - 1];
}

__global__ __launch_bounds__(512) void k_scan3(const int* __restrict__ counts,
                                               const int* __restrict__ boff,
                                               int* __restrict__ csr_off,
                                               int* __restrict__ cursor) {
    int t = threadIdx.x;
    int i = blockIdx.x * 512 + t;
    int v = (i < N_NODES) ? counts[i] : 0;
    int lane = t & 63, w = t >> 6;
    int xs = v;
    #pragma unroll
    for (int o = 1; o < 64; o <<= 1) {
        int u = __shfl_up(xs, o);
        if (lane >= o) xs += u;
    }
    __shared__ int ws[8];
    __shared__ int wo[8];
    if (lane == 63) ws[w] = xs;
    __syncthreads();
    if (t == 0) {
        int s = 0;
        #pragma unroll
        for (int k = 0; k < 8; ++k) { wo[k] = s; s += ws[k]; }
    }
    __syncthreads();
    int excl = xs - v + wo[w] + boff[blockIdx.x];
    if (i < N_NODES) { csr_off[i] = excl; cursor[i] = excl; }
    if (i == N_NODES) csr_off[N_NODES] = E_EDGES;
}

// ---------------- fill CSR with src ids ----------------
__global__ void k_fill(const int* __restrict__ es, const int* __restrict__ ed,
                       int* __restrict__ cursor, int* __restrict__ csr_src) {
    int e = blockIdx.x * 256 + threadIdx.x;
    if (e < E_EDGES) {
        int pos = atomicAdd(&cursor[ed[e]], 1);
        csr_src[pos] = es[e];
    }
}

// ---------------- weight prep: transpose + bf16 ----------------
__global__ void k_prep(const float* __restrict__ W1, const float* __restrict__ W2,
                       const float* __restrict__ Wfc,
                       bf16_t* __restrict__ W1T, bf16_t* __restrict__ W2T,
                       bf16_t* __restrict__ WpT) {
    int id = blockIdx.x * 256 + threadIdx.x;
    if (id < 512 * 128) {
        int c = id >> 7, k = id & 127;
        W1T[id] = (bf16_t)W1[(size_t)k * 512 + c];
        int c2 = id >> 9, k2 = id & 511;
        W2T[id] = (bf16_t)W2[(size_t)k2 * 128 + c2];
        if (id < 128 * 128) {
            int cp = id >> 7, kp = id & 127;
            WpT[id] = (bf16_t)Wfc[(cp >> 4) * 2048 + kp * 16 + (cp & 15)];
        }
    }
}

// ---------------- z = x @ Wp via bf16 MFMA + fused el/er + zb ----------------
__global__ __launch_bounds__(512) void k_proj(const float* __restrict__ x,
                                              const bf16_t* __restrict__ WpT,
                                              const float* __restrict__ a_l,
                                              const float* __restrict__ a_r,
                                              unsigned short* __restrict__ zb,
                                              float* __restrict__ el,
                                              float* __restrict__ er) {
    __shared__ char xbA[16384];  // bf16[64][128], row stride 256B, swizzled
    int t = threadIdx.x;
    int r0 = blockIdx.x * 64;

    {
        int r = t >> 3, c0 = (t & 7) * 16;
        int gr = r0 + r;
        u16x8 pk0, pk1;
        if (gr < N_NODES) {
            #pragma unroll
            for (int q = 0; q < 2; ++q) {
                float4 a4 = *(const float4*)&x[(size_t)gr * 128 + c0 + q * 8];
                float4 b4 = *(const float4*)&x[(size_t)gr * 128 + c0 + q * 8 + 4];
                u16x8 pk;
                pk[0] = f2b(a4.x); pk[1] = f2b(a4.y); pk[2] = f2b(a4.z); pk[3] = f2b(a4.w);
                pk[4] = f2b(b4.x); pk[5] = f2b(b4.y); pk[6] = f2b(b4.z); pk[7] = f2b(b4.w);
                if (q == 0) pk0 = pk; else pk1 = pk;
            }
        } else {
            #pragma unroll
            for (int i = 0; i < 8; ++i) { pk0[i] = 0; pk1[i] = 0; }
        }
        int base = r * 256 + c0 * 2;
        *(u16x8*)(xbA + (base ^ SWZ(r))) = pk0;
        *(u16x8*)(xbA + ((base + 16) ^ SWZ(r))) = pk1;
    }
    __syncthreads();

    int wv = t >> 6, l = t & 63;
    int lr = l & 15, lg = l >> 4;

    f32x4 acc[4] = {};
    #pragma unroll
    for (int ks = 0; ks < 4; ++ks) {
        bf16x8 b = *(const bf16x8*)(WpT + (wv * 16 + lr) * 128 + ks * 32 + lg * 8);
        #pragma unroll
        for (int mi = 0; mi < 4; ++mi) {
            int row = mi * 16 + lr;
            int off = (row * 256 + ks * 64 + lg * 16) ^ SWZ(row);
            bf16x8 a = *(const bf16x8*)(xbA + off);
            acc[mi] = __builtin_amdgcn_mfma_f32_16x16x32_bf16(a, b, acc[mi], 0, 0, 0);
        }
    }

    float alv = a_l[wv * 16 + lr];
    float arv = a_r[wv * 16 + lr];
    float outL = 0.f, outR = 0.f;
    #pragma unroll
    for (int mi = 0; mi < 4; ++mi) {
        #pragma unroll
        for (int rg = 0; rg < 4; ++rg) {
            int row = mi * 16 + lg * 4 + rg;
            int grr = r0 + row;
            float v = acc[mi][rg];
            if (grr < N_NODES) zb[(size_t)grr * 128 + wv * 16 + lr] = f2b(v);
            float pl = v * alv, pr = v * arv;
            pl += __shfl_xor(pl, 1); pr += __shfl_xor(pr, 1);
            pl += __shfl_xor(pl, 2); pr += __shfl_xor(pr, 2);
            pl += __shfl_xor(pl, 4); pr += __shfl_xor(pr, 4);
            pl += __shfl_xor(pl, 8); pr += __shfl_xor(pr, 8);
            if (lr == mi * 4 + rg) { outL = pl; outR = pr; }
        }
    }
    int myrow = r0 + (lr >> 2) * 16 + lg * 4 + (lr & 3);
    if (myrow < N_NODES) {
        el[myrow * 8 + wv] = outL;
        er[myrow * 8 + wv] = outR;
    }
}

// ---------------- fused per-node softmax + aggregate + elu + residual -------
// Writes h = x + elu(agg) so k_ffn needs only one input stream.
__global__ __launch_bounds__(256) void k_node(const int* __restrict__ csr_off,
                                              const int* __restrict__ csr_src,
                                              const float* __restrict__ el,
                                              const float* __restrict__ er,
                                              const unsigned short* __restrict__ zb,
                                              const float* __restrict__ x,
                                              float* __restrict__ out) {
    int n = blockIdx.x * 4 + (threadIdx.x >> 6);
    if (n >= N_NODES) return;
    int lane = threadIdx.x & 63;
    int h = lane >> 3, s = lane & 7;
    int row = csr_off[n];
    int deg = csr_off[n + 1] - row;
    float2 xv = *(const float2*)&x[(size_t)n * 128 + lane * 2];
    if (deg == 0) {
        *(float2*)&out[(size_t)n * 128 + lane * 2] = xv;  // h = x + elu(0)
        return;
    }
    float erv = er[n * 8 + h];
    int nch = (deg + 7) >> 3;

    // pass 1: static 8 chunks in registers + running max
    float ev[8];
    int srcv[8];
    float mx = -INFINITY;
    #pragma unroll
    for (int c = 0; c < 8; ++c) {
        int k = c * 8 + s;
        int src = 0;
        float e = -INFINITY;
        if (c * 8 < deg) {  // uniform across wave
            if (k < deg) {
                src = csr_src[row + k];
                e = lrelu(el[src * 8 + h] + erv);
            }
        }
        ev[c] = e;
        srcv[c] = src;
        mx = fmaxf(mx, e);
    }
    for (int c = 8; c < nch; ++c) {  // rare: deg > 64
        int k = c * 8 + s;
        if (k < deg) {
            int src = csr_src[row + k];
            mx = fmaxf(mx, lrelu(el[src * 8 + h] + erv));
        }
    }
    mx = fmaxf(mx, __shfl_xor(mx, 1));
    mx = fmaxf(mx, __shfl_xor(mx, 2));
    mx = fmaxf(mx, __shfl_xor(mx, 4));

    // pass 2: exp + sum + gather-aggregate
    float ps = 0.f;
    float2 acc = make_float2(0.f, 0.f);
    const unsigned short* zbl = zb + lane * 2;
    #pragma unroll
    for (int c = 0; c < 8; ++c) {
        if (c * 8 < deg) {  // uniform
            float p = ((c * 8 + s) < deg) ? __expf(ev[c] - mx) : 0.f;
            ps += p;
            float a[8];
            int se[8];
            #pragma unroll
            for (int tt = 0; tt < 8; ++tt) {
                a[tt] = __shfl(p, h * 8 + tt);
                se[tt] = __shfl(srcv[c], h * 8 + tt);
            }
            unsigned u[8];
            #pragma unroll
            for (int tt = 0; tt < 8; ++tt)
                u[tt] = *(const unsigned*)(zbl + (size_t)se[tt] * 128);
            #pragma unroll
            for (int tt = 0; tt < 8; ++tt) {
                acc.x += a[tt] * __uint_as_float(u[tt] << 16);
                acc.y += a[tt] * __uint_as_float(u[tt] & 0xFFFF0000u);
            }
        }
    }
    for (int c = 8; c < nch; ++c) {  // rare: deg > 64
        int k = c * 8 + s;
        int src = 0;
        float e = -INFINITY;
        if (k < deg) {
            src = csr_src[row + k];
            e = lrelu(el[src * 8 + h] + erv);
        }
        float p = (k < deg) ? __expf(e - mx) : 0.f;
        ps += p;
        float a[8];
        int se[8];
        #pragma unroll
        for (int tt = 0; tt < 8; ++tt) {
            a[tt] = __shfl(p, h * 8 + tt);
            se[tt] = __shfl(src, h * 8 + tt);
        }
        unsigned u[8];
        #pragma unroll
        for (int tt = 0; tt < 8; ++tt)
            u[tt] = *(const unsigned*)(zbl + (size_t)se[tt] * 128);
        #pragma unroll
        for (int tt = 0; tt < 8; ++tt) {
            acc.x += a[tt] * __uint_as_float(u[tt] << 16);
            acc.y += a[tt] * __uint_as_float(u[tt] & 0xFFFF0000u);
        }
    }
    ps += __shfl_xor(ps, 1);
    ps += __shfl_xor(ps, 2);
    ps += __shfl_xor(ps, 4);
    float sumh = __shfl(ps, h * 8);
    float inv = 1.f / fmaxf(sumh, 1e-9f);
    float2 hv;
    hv.x = xv.x + elu(acc.x * inv);
    hv.y = xv.y + elu(acc.y * inv);
    *(float2*)&out[(size_t)n * 128 + lane * 2] = hv;
}

// ---------------- fused LN+FFN with bf16 MFMA (input h in `out`) ------------
// Single-pass: lnA 16KB + inA 64KB = 80KB -> 2 blocks/CU (LDS-bound; no VGPR cap).
// GEMM2 split 2rows x 4cols per wave: 32 ds_read / 64 MFMA. W1/W2 frags hoisted.
__global__ __launch_bounds__(512) void k_ffn(const float* __restrict__ gamma,
                                             const float* __restrict__ beta,
                                             const bf16_t* __restrict__ W1T,
                                             const float* __restrict__ b1,
                                             const bf16_t* __restrict__ W2T,
                                             const float* __restrict__ b2,
                                             float* __restrict__ out) {
    __shared__ char smem[81920];
    char* lnA = smem;           // bf16[64][128], row stride 256B, swizzled
    char* inA = smem + 16384;   // bf16[64][512], row stride 1024B, swizzled
    int t = threadIdx.x;
    int r0 = blockIdx.x * 64;
    int wv = t >> 6, l = t & 63;
    int lr = l & 15, lg = l >> 4;

    // hoist W1 fragments (latency overlaps phase 0)
    bf16x8 bW1[4][4];
    #pragma unroll
    for (int ks = 0; ks < 4; ++ks)
        #pragma unroll
        for (int ni = 0; ni < 4; ++ni)
            bW1[ks][ni] = *(const bf16x8*)(W1T + (size_t)(wv * 64 + ni * 16 + lr) * 128 + ks * 32 + lg * 8);

    // phase 0: read h (= out), LN in registers, ln -> lnA (bf16, swizzled)
    {
        int r = t >> 3, c0 = (t & 7) * 16;
        int gr = r0 + r;
        float hv[16];
        if (gr < N_NODES) {
            #pragma unroll
            for (int q = 0; q < 4; ++q) {
                float4 h4 = *(const float4*)&out[(size_t)gr * 128 + c0 + q * 4];
                hv[q * 4 + 0] = h4.x; hv[q * 4 + 1] = h4.y;
                hv[q * 4 + 2] = h4.z; hv[q * 4 + 3] = h4.w;
            }
        } else {
            #pragma unroll
            for (int i = 0; i < 16; ++i) hv[i] = 0.f;
        }
        float sm = 0.f, sq = 0.f;
        #pragma unroll
        for (int i = 0; i < 16; ++i) { sm += hv[i]; sq += hv[i] * hv[i]; }
        sm += __shfl_xor(sm, 1); sq += __shfl_xor(sq, 1);
        sm += __shfl_xor(sm, 2); sq += __shfl_xor(sq, 2);
        sm += __shfl_xor(sm, 4); sq += __shfl_xor(sq, 4);
        float mu = sm * (1.f / 128.f);
        float rs = rsqrtf(sq * (1.f / 128.f) - mu * mu + 1e-5f);
        u16x8 pk0, pk1;
        #pragma unroll
        for (int i = 0; i < 8; ++i) {
            pk0[i] = f2b((hv[i] - mu) * rs * gamma[c0 + i] + beta[c0 + i]);
            pk1[i] = f2b((hv[8 + i] - mu) * rs * gamma[c0 + 8 + i] + beta[c0 + 8 + i]);
        }
        int base = r * 256 + c0 * 2;
        *(u16x8*)(lnA + (base ^ SWZ(r))) = pk0;
        *(u16x8*)(lnA + ((base + 16) ^ SWZ(r))) = pk1;
    }
    __syncthreads();

    // GEMM1: inter[64][512] = relu(ln @ W1 + b1); wave covers cols [wv*64,+64)
    f32x4 acc[4][4] = {};
    #pragma unroll
    for (int ks = 0; ks < 4; ++ks) {
        bf16x8 a[4];
        #pragma unroll
        for (int mi = 0; mi < 4; ++mi) {
            int row = mi * 16 + lr;
            int off = (row * 256 + ks * 64 + lg * 16) ^ SWZ(row);
            a[mi] = *(const bf16x8*)(lnA + off);
        }
        #pragma unroll
        for (int mi = 0; mi < 4; ++mi)
            #pragma unroll
            for (int ni = 0; ni < 4; ++ni)
                acc[mi][ni] = __builtin_amdgcn_mfma_f32_16x16x32_bf16(
                    a[mi], bW1[ks][ni], acc[mi][ni], 0, 0, 0);
    }

    // hoist W2 fragments for this wave's GEMM2 tile (latency overlaps inA writes)
    int rh = wv >> 2, cq = wv & 3;
    bf16x8 bW2[16][2];
    #pragma unroll
    for (int ks = 0; ks < 16; ++ks)
        #pragma unroll
        for (int ni = 0; ni < 2; ++ni)
            bW2[ks][ni] = *(const bf16x8*)(W2T + (size_t)(cq * 32 + ni * 16 + lr) * 512 + ks * 32 + lg * 8);

    // bias + relu -> inA (bf16, swizzled)
    #pragma unroll
    for (int ni = 0; ni < 4; ++ni) {
        int c = wv * 64 + ni * 16 + lr;
        float bb = b1[c];
        #pragma unroll
        for (int mi = 0; mi < 4; ++mi) {
            #pragma unroll
            for (int rg = 0; rg < 4; ++rg) {
                int row = mi * 16 + lg * 4 + rg;
                float v = acc[mi][ni][rg] + bb;
                v = v > 0.f ? v : 0.f;
                *(unsigned short*)(inA + ((row * 1024 + c * 2) ^ SWZ(row))) = f2b(v);
            }
        }
    }
    __syncthreads();

    // GEMM2: wave covers rows [rh*32,+32) x cols [cq*32,+32)
    f32x4 acc2[2][2] = {};
    #pragma unroll
    for (int ks = 0; ks < 16; ++ks) {
        bf16x8 a2[2];
        #pragma unroll
        for (int mi = 0; mi < 2; ++mi) {
            int row = rh * 32 + mi * 16 + lr;
            int off = (row * 1024 + ks * 64 + lg * 16) ^ SWZ(row);
            a2[mi] = *(const bf16x8*)(inA + off);
        }
        #pragma unroll
        for (int mi = 0; mi < 2; ++mi)
            #pragma unroll
            for (int ni = 0; ni < 2; ++ni)
                acc2[mi][ni] = __builtin_amdgcn_mfma_f32_16x16x32_bf16(
                    a2[mi], bW2[ks][ni], acc2[mi][ni], 0, 0, 0);
    }

    // epilogue: out = acc2 + b2 + h (h re-read from out, L2/L3-hot)
    #pragma unroll
    for (int ni = 0; ni < 2; ++ni) {
        int col = cq * 32 + ni * 16 + lr;
        float bb2 = b2[col];
        #pragma unroll
        for (int mi = 0; mi < 2; ++mi) {
            #pragma unroll
            for (int rg = 0; rg < 4; ++rg) {
                int row = rh * 32 + mi * 16 + lg * 4 + rg;
                int gr = r0 + row;
                if (gr < N_NODES) {
                    size_t idx = (size_t)gr * 128 + col;
                    out[idx] = acc2[mi][ni][rg] + bb2 + out[idx];
                }
            }
        }
    }
}

extern "C" void kernel_launch(void* const* d_in, const int* in_sizes, int n_in,
                              void* d_out, int out_size, void* d_ws, size_t ws_size,
                              hipStream_t stream) {
    const float* x     = (const float*)d_in[0];
    const float* Wfc   = (const float*)d_in[1];
    const float* a_l   = (const float*)d_in[2];
    const float* a_r   = (const float*)d_in[3];
    const float* gamma = (const float*)d_in[4];
    const float* beta  = (const float*)d_in[5];
    const float* W1    = (const float*)d_in[6];
    const float* b1    = (const float*)d_in[7];
    const float* W2    = (const float*)d_in[8];
    const float* b2    = (const float*)d_in[9];
    const int*   es    = (const int*)d_in[10];
    const int*   ed    = (const int*)d_in[11];
    float* out = (float*)d_out;

    bf16_t* W1T = (bf16_t*)d_ws;                      // 512*128
    bf16_t* W2T = W1T + 512 * 128;                    // 128*512
    bf16_t* WpT = W2T + 128 * 512;                    // 128*128
    unsigned short* zb = (unsigned short*)(WpT + 128 * 128);  // N*128 bf16
    float* el = (float*)(zb + (size_t)N_NODES * 128); // N*8
    float* er = el + N_NODES * 8;                     // N*8
    int* counts  = (int*)(er + N_NODES * 8);          // N
    int* csr_off = counts + N_NODES;                  // N+1
    int* cursor  = csr_off + N_NODES + 1;             // N+1
    int* csr_src = cursor + N_NODES + 1;              // E
    int* bsum    = csr_src + E_EDGES;                 // SCAN_BLOCKS
    int* boff    = bsum + 128;                        // 128

    k_zero<<<dim3((N_NODES + 255) / 256), dim3(256), 0, stream>>>(counts);
    k_count<<<dim3((E_EDGES + 255) / 256), dim3(256), 0, stream>>>(ed, counts);
    k_scan1<<<dim3(SCAN_BLOCKS), dim3(512), 0, stream>>>(counts, bsum);
    k_scan2<<<dim3(1), dim3(128), 0, stream>>>(bsum, boff);
    k_scan3<<<dim3(SCAN_BLOCKS), dim3(512), 0, stream>>>(counts, boff, csr_off, cursor);
    k_fill<<<dim3((E_EDGES + 255) / 256), dim3(256), 0, stream>>>(es, ed, cursor, csr_src);
    k_prep<<<dim3(256), dim3(256), 0, stream>>>(W1, W2, Wfc, W1T, W2T, WpT);
    k_proj<<<dim3((N_NODES + 63) / 64), dim3(512), 0, stream>>>(x, WpT, a_l, a_r, zb, el, er);
    k_node<<<dim3((N_NODES + 3) / 4), dim3(256), 0, stream>>>(csr_off, csr_src, el, er, zb, x, out);
    k_ffn<<<dim3((N_NODES + 63) / 64), dim3(512), 0, stream>>>(gamma, beta, W1T, b1, W2T, b2, out);
}

// Round 10
// 232.804 us; speedup vs baseline: 1.2210x; 1.0068x over previous
//
#include <hip/hip_runtime.h>
#include <math.h>

#define N_NODES 50000
#define E_EDGES 800000
#define D_DIM   128
#define H_HEADS 8
#define DH_DIM  16
#define DFF     512

#define SCAN_BLOCKS 98  // 98*512 = 50176 >= N_NODES+1

typedef __bf16 bf16_t;
typedef bf16_t bf16x8 __attribute__((ext_vector_type(8)));
typedef float f32x4 __attribute__((ext_vector_type(4)));
typedef unsigned short u16x8 __attribute__((ext_vector_type(8)));

#define SWZ(r) (((r) & 7) << 4)

__device__ __forceinline__ float lrelu(float v) { return v > 0.f ? v : 0.01f * v; }
__device__ __forceinline__ float elu(float v) { return v > 0.f ? v : __expf(v) - 1.f; }
__device__ __forceinline__ unsigned short f2b(float f) {
    unsigned u = __float_as_uint(f);
    unsigned r = (u + 0x7FFFu + ((u >> 16) & 1u)) >> 16;
    return (unsigned short)r;
}

// ---------------- zero counts ----------------
__global__ void k_zero(int* __restrict__ counts) {
    int i = blockIdx.x * 256 + threadIdx.x;
    if (i < N_NODES) counts[i] = 0;
}

// ---------------- count in-degree ----------------
__global__ void k_count(const int* __restrict__ ed, int* __restrict__ counts) {
    int e = blockIdx.x * 256 + threadIdx.x;
    if (e < E_EDGES) atomicAdd(&counts[ed[e]], 1);
}

// ---------------- hierarchical scan ----------------
__global__ __launch_bounds__(512) void k_scan1(const int* __restrict__ counts,
                                               int* __restrict__ bsum) {
    int i = blockIdx.x * 512 + threadIdx.x;
    int v = (i < N_NODES) ? counts[i] : 0;
    #pragma unroll
    for (int o = 1; o < 64; o <<= 1) v += __shfl_xor(v, o);
    __shared__ int ws[8];
    if ((threadIdx.x & 63) == 0) ws[threadIdx.x >> 6] = v;
    __syncthreads();
    if (threadIdx.x == 0) {
        int s = 0;
        #pragma unroll
        for (int k = 0; k < 8; ++k) s += ws[k];
        bsum[blockIdx.x] = s;
    }
}

__global__ __launch_bounds__(128) void k_scan2(const int* __restrict__ bsum,
                                               int* __restrict__ boff) {
    __shared__ int tmp[128];
    int t = threadIdx.x;
    int v = (t < SCAN_BLOCKS) ? bsum[t] : 0;
    tmp[t] = v;
    __syncthreads();
    for (int o = 1; o < 128; o <<= 1) {
        int u = (t >= o) ? tmp[t - o] : 0;
        __syncthreads();
        tmp[t] += u;
        __syncthreads();
    }
    boff[t] = (t == 0) ? 0 : tmp[t - 1];
}

__global__ __launch_bounds__(512) void k_scan3(const int* __restrict__ counts,
                                               const int* __restrict__ boff,
                                               int* __restrict__ csr_off,
                                               int* __restrict__ cursor) {
    int t = threadIdx.x;
    int i = blockIdx.x * 512 + t;
    int v = (i < N_NODES) ? counts[i] : 0;
    int lane = t & 63, w = t >> 6;
    int xs = v;
    #pragma unroll
    for (int o = 1; o < 64; o <<= 1) {
        int u = __shfl_up(xs, o);
        if (lane >= o) xs += u;
    }
    __shared__ int ws[8];
    __shared__ int wo[8];
    if (lane == 63) ws[w] = xs;
    __syncthreads();
    if (t == 0) {
        int s = 0;
        #pragma unroll
        for (int k = 0; k < 8; ++k) { wo[k] = s; s += ws[k]; }
    }
    __syncthreads();
    int excl = xs - v + wo[w] + boff[blockIdx.x];
    if (i < N_NODES) { csr_off[i] = excl; cursor[i] = excl; }
    if (i == N_NODES) csr_off[N_NODES] = E_EDGES;
}

// ---------------- fill CSR with src ids ----------------
__global__ void k_fill(const int* __restrict__ es, const int* __restrict__ ed,
                       int* __restrict__ cursor, int* __restrict__ csr_src) {
    int e = blockIdx.x * 256 + threadIdx.x;
    if (e < E_EDGES) {
        int pos = atomicAdd(&cursor[ed[e]], 1);
        csr_src[pos] = es[e];
    }
}

// ---------------- weight prep: transpose + bf16 ----------------
__global__ void k_prep(const float* __restrict__ W1, const float* __restrict__ W2,
                       const float* __restrict__ Wfc,
                       bf16_t* __restrict__ W1T, bf16_t* __restrict__ W2T,
                       bf16_t* __restrict__ WpT) {
    int id = blockIdx.x * 256 + threadIdx.x;
    if (id < 512 * 128) {
        int c = id >> 7, k = id & 127;
        W1T[id] = (bf16_t)W1[(size_t)k * 512 + c];
        int c2 = id >> 9, k2 = id & 511;
        W2T[id] = (bf16_t)W2[(size_t)k2 * 128 + c2];
        if (id < 128 * 128) {
            int cp = id >> 7, kp = id & 127;
            WpT[id] = (bf16_t)Wfc[(cp >> 4) * 2048 + kp * 16 + (cp & 15)];
        }
    }
}

// ---------------- z = x @ Wp via bf16 MFMA + fused el/er + zb ----------------
__global__ __launch_bounds__(512) void k_proj(const float* __restrict__ x,
                                              const bf16_t* __restrict__ WpT,
                                              const float* __restrict__ a_l,
                                              const float* __restrict__ a_r,
                                              unsigned short* __restrict__ zb,
                                              float* __restrict__ el,
                                              float* __restrict__ er) {
    __shared__ char xbA[16384];  // bf16[64][128], row stride 256B, swizzled
    int t = threadIdx.x;
    int r0 = blockIdx.x * 64;

    {
        int r = t >> 3, c0 = (t & 7) * 16;
        int gr = r0 + r;
        u16x8 pk0, pk1;
        if (gr < N_NODES) {
            #pragma unroll
            for (int q = 0; q < 2; ++q) {
                float4 a4 = *(const float4*)&x[(size_t)gr * 128 + c0 + q * 8];
                float4 b4 = *(const float4*)&x[(size_t)gr * 128 + c0 + q * 8 + 4];
                u16x8 pk;
                pk[0] = f2b(a4.x); pk[1] = f2b(a4.y); pk[2] = f2b(a4.z); pk[3] = f2b(a4.w);
                pk[4] = f2b(b4.x); pk[5] = f2b(b4.y); pk[6] = f2b(b4.z); pk[7] = f2b(b4.w);
                if (q == 0) pk0 = pk; else pk1 = pk;
            }
        } else {
            #pragma unroll
            for (int i = 0; i < 8; ++i) { pk0[i] = 0; pk1[i] = 0; }
        }
        int base = r * 256 + c0 * 2;
        *(u16x8*)(xbA + (base ^ SWZ(r))) = pk0;
        *(u16x8*)(xbA + ((base + 16) ^ SWZ(r))) = pk1;
    }
    __syncthreads();

    int wv = t >> 6, l = t & 63;
    int lr = l & 15, lg = l >> 4;

    f32x4 acc[4] = {};
    #pragma unroll
    for (int ks = 0; ks < 4; ++ks) {
        bf16x8 b = *(const bf16x8*)(WpT + (wv * 16 + lr) * 128 + ks * 32 + lg * 8);
        #pragma unroll
        for (int mi = 0; mi < 4; ++mi) {
            int row = mi * 16 + lr;
            int off = (row * 256 + ks * 64 + lg * 16) ^ SWZ(row);
            bf16x8 a = *(const bf16x8*)(xbA + off);
            acc[mi] = __builtin_amdgcn_mfma_f32_16x16x32_bf16(a, b, acc[mi], 0, 0, 0);
        }
    }

    float alv = a_l[wv * 16 + lr];
    float arv = a_r[wv * 16 + lr];
    float outL = 0.f, outR = 0.f;
    #pragma unroll
    for (int mi = 0; mi < 4; ++mi) {
        #pragma unroll
        for (int rg = 0; rg < 4; ++rg) {
            int row = mi * 16 + lg * 4 + rg;
            int grr = r0 + row;
            float v = acc[mi][rg];
            if (grr < N_NODES) zb[(size_t)grr * 128 + wv * 16 + lr] = f2b(v);
            float pl = v * alv, pr = v * arv;
            pl += __shfl_xor(pl, 1); pr += __shfl_xor(pr, 1);
            pl += __shfl_xor(pl, 2); pr += __shfl_xor(pr, 2);
            pl += __shfl_xor(pl, 4); pr += __shfl_xor(pr, 4);
            pl += __shfl_xor(pl, 8); pr += __shfl_xor(pr, 8);
            if (lr == mi * 4 + rg) { outL = pl; outR = pr; }
        }
    }
    int myrow = r0 + (lr >> 2) * 16 + lg * 4 + (lr & 3);
    if (myrow < N_NODES) {
        el[myrow * 8 + wv] = outL;
        er[myrow * 8 + wv] = outR;
    }
}

// ---------------- fused softmax + aggregate + elu + residual ----------------
// TWO nodes per wave (one per half-wave): 2 independent dep chains, 8B gathers.
// Half-wave lane q = h*4 + s (8 heads x 4 edge slots); output dims 4q..4q+3.
__global__ __launch_bounds__(256) void k_node(const int* __restrict__ csr_off,
                                              const int* __restrict__ csr_src,
                                              const float* __restrict__ el,
                                              const float* __restrict__ er,
                                              const unsigned short* __restrict__ zb,
                                              const float* __restrict__ x,
                                              float* __restrict__ out) {
    int n = blockIdx.x * 8 + (threadIdx.x >> 5);
    int lane = threadIdx.x & 63;
    int q = lane & 31;
    int base = lane & 32;       // shuffle base of this half-wave
    int h = q >> 2, s = q & 3;
    int row = csr_off[n];
    int deg = csr_off[n + 1] - row;
    float4 xv = *(const float4*)&x[(size_t)n * 128 + q * 4];
    float erv = er[n * 8 + h];
    int nch = (deg + 3) >> 2;

    // pass 1: static 8 chunks (4 edges each) in registers + running max
    float ev[8];
    int srcv[8];
    float mx = -INFINITY;
    #pragma unroll
    for (int c = 0; c < 8; ++c) {
        int k = c * 4 + s;
        int src = 0;
        float e = -INFINITY;
        if (c * 4 < deg) {  // uniform across half-wave
            if (k < deg) {
                src = csr_src[row + k];
                e = lrelu(el[src * 8 + h] + erv);
            }
        }
        ev[c] = e;
        srcv[c] = src;
        mx = fmaxf(mx, e);
    }
    for (int c = 8; c < nch; ++c) {  // rare: deg > 32
        int k = c * 4 + s;
        if (k < deg) {
            int src = csr_src[row + k];
            mx = fmaxf(mx, lrelu(el[src * 8 + h] + erv));
        }
    }
    mx = fmaxf(mx, __shfl_xor(mx, 1));
    mx = fmaxf(mx, __shfl_xor(mx, 2));

    // pass 2: exp + sum + gather-aggregate (8B gathers, 4 dims/lane)
    float ps = 0.f;
    float ac0 = 0.f, ac1 = 0.f, ac2 = 0.f, ac3 = 0.f;
    const unsigned short* zbl = zb + q * 4;
    #pragma unroll
    for (int c = 0; c < 8; ++c) {
        if (c * 4 < deg) {  // uniform across half-wave
            float p = ((c * 4 + s) < deg) ? __expf(ev[c] - mx) : 0.f;
            ps += p;
            float a[4];
            int se[4];
            #pragma unroll
            for (int tt = 0; tt < 4; ++tt) {
                a[tt] = __shfl(p, base + h * 4 + tt);
                se[tt] = __shfl(srcv[c], base + tt);
            }
            uint2 u[4];
            #pragma unroll
            for (int tt = 0; tt < 4; ++tt)
                u[tt] = *(const uint2*)(zbl + (size_t)se[tt] * 128);
            #pragma unroll
            for (int tt = 0; tt < 4; ++tt) {
                ac0 += a[tt] * __uint_as_float(u[tt].x << 16);
                ac1 += a[tt] * __uint_as_float(u[tt].x & 0xFFFF0000u);
                ac2 += a[tt] * __uint_as_float(u[tt].y << 16);
                ac3 += a[tt] * __uint_as_float(u[tt].y & 0xFFFF0000u);
            }
        }
    }
    for (int c = 8; c < nch; ++c) {  // rare: deg > 32
        int k = c * 4 + s;
        int src = 0;
        float e = -INFINITY;
        if (k < deg) {
            src = csr_src[row + k];
            e = lrelu(el[src * 8 + h] + erv);
        }
        float p = (k < deg) ? __expf(e - mx) : 0.f;
        ps += p;
        float a[4];
        int se[4];
        #pragma unroll
        for (int tt = 0; tt < 4; ++tt) {
            a[tt] = __shfl(p, base + h * 4 + tt);
            se[tt] = __shfl(src, base + tt);
        }
        uint2 u[4];
        #pragma unroll
        for (int tt = 0; tt < 4; ++tt)
            u[tt] = *(const uint2*)(zbl + (size_t)se[tt] * 128);
        #pragma unroll
        for (int tt = 0; tt < 4; ++tt) {
            ac0 += a[tt] * __uint_as_float(u[tt].x << 16);
            ac1 += a[tt] * __uint_as_float(u[tt].x & 0xFFFF0000u);
            ac2 += a[tt] * __uint_as_float(u[tt].y << 16);
            ac3 += a[tt] * __uint_as_float(u[tt].y & 0xFFFF0000u);
        }
    }
    ps += __shfl_xor(ps, 1);
    ps += __shfl_xor(ps, 2);
    // ps is now this head's sum; lane q's output head == h. deg==0 -> ps=0 -> acc*inv=0.
    float inv = 1.f / fmaxf(ps, 1e-9f);
    float4 hv;
    hv.x = xv.x + elu(ac0 * inv);
    hv.y = xv.y + elu(ac1 * inv);
    hv.z = xv.z + elu(ac2 * inv);
    hv.w = xv.w + elu(ac3 * inv);
    *(float4*)&out[(size_t)n * 128 + q * 4] = hv;
}

// ---------------- fused LN+FFN with bf16 MFMA (input h in `out`) ------------
// 32 rows/block, 256 threads (4 waves). LDS: lnA 8KB + inA 32KB = 40KB
// -> 4 blocks/CU, 1563 blocks: concurrency fix for the latency-bound profile.
__global__ __launch_bounds__(256) void k_ffn(const float* __restrict__ gamma,
                                             const float* __restrict__ beta,
                                             const bf16_t* __restrict__ W1T,
                                             const float* __restrict__ b1,
                                             const bf16_t* __restrict__ W2T,
                                             const float* __restrict__ b2,
                                             float* __restrict__ out) {
    __shared__ char smem[40960];
    char* lnA = smem;          // bf16[32][128], row stride 256B, swizzled
    char* inA = smem + 8192;   // bf16[32][512], row stride 1024B, swizzled
    int t = threadIdx.x;
    int r0 = blockIdx.x * 32;
    int wv = t >> 6, l = t & 63;
    int lr = l & 15, lg = l >> 4;

    // phase 0: read h (= out), LN in registers, ln -> lnA (bf16, swizzled)
    {
        int r = t >> 3, c0 = (t & 7) * 16;
        int gr = r0 + r;
        float hv[16];
        if (gr < N_NODES) {
            #pragma unroll
            for (int qq = 0; qq < 4; ++qq) {
                float4 h4 = *(const float4*)&out[(size_t)gr * 128 + c0 + qq * 4];
                hv[qq * 4 + 0] = h4.x; hv[qq * 4 + 1] = h4.y;
                hv[qq * 4 + 2] = h4.z; hv[qq * 4 + 3] = h4.w;
            }
        } else {
            #pragma unroll
            for (int i = 0; i < 16; ++i) hv[i] = 0.f;
        }
        float sm = 0.f, sq = 0.f;
        #pragma unroll
        for (int i = 0; i < 16; ++i) { sm += hv[i]; sq += hv[i] * hv[i]; }
        sm += __shfl_xor(sm, 1); sq += __shfl_xor(sq, 1);
        sm += __shfl_xor(sm, 2); sq += __shfl_xor(sq, 2);
        sm += __shfl_xor(sm, 4); sq += __shfl_xor(sq, 4);
        float mu = sm * (1.f / 128.f);
        float rs = rsqrtf(sq * (1.f / 128.f) - mu * mu + 1e-5f);
        u16x8 pk0, pk1;
        #pragma unroll
        for (int i = 0; i < 8; ++i) {
            pk0[i] = f2b((hv[i] - mu) * rs * gamma[c0 + i] + beta[c0 + i]);
            pk1[i] = f2b((hv[8 + i] - mu) * rs * gamma[c0 + 8 + i] + beta[c0 + 8 + i]);
        }
        int base = r * 256 + c0 * 2;
        *(u16x8*)(lnA + (base ^ SWZ(r))) = pk0;
        *(u16x8*)(lnA + ((base + 16) ^ SWZ(r))) = pk1;
    }
    __syncthreads();

    // GEMM1: inter[32][512] = relu(ln @ W1 + b1); two 256-col passes,
    // wave covers 64 cols per pass (acc[2][4], modest registers).
    #pragma unroll
    for (int fp = 0; fp < 2; ++fp) {
        f32x4 acc[2][4] = {};
        #pragma unroll
        for (int ks = 0; ks < 4; ++ks) {
            bf16x8 a[2], b[4];
            #pragma unroll
            for (int mi = 0; mi < 2; ++mi) {
                int row = mi * 16 + lr;
                int off = (row * 256 + ks * 64 + lg * 16) ^ SWZ(row);
                a[mi] = *(const bf16x8*)(lnA + off);
            }
            #pragma unroll
            for (int ni = 0; ni < 4; ++ni) {
                int c = fp * 256 + wv * 64 + ni * 16 + lr;
                b[ni] = *(const bf16x8*)(W1T + (size_t)c * 128 + ks * 32 + lg * 8);
            }
            #pragma unroll
            for (int mi = 0; mi < 2; ++mi)
                #pragma unroll
                for (int ni = 0; ni < 4; ++ni)
                    acc[mi][ni] = __builtin_amdgcn_mfma_f32_16x16x32_bf16(
                        a[mi], b[ni], acc[mi][ni], 0, 0, 0);
        }
        #pragma unroll
        for (int ni = 0; ni < 4; ++ni) {
            int c = fp * 256 + wv * 64 + ni * 16 + lr;
            float bb = b1[c];
            #pragma unroll
            for (int mi = 0; mi < 2; ++mi) {
                #pragma unroll
                for (int rg = 0; rg < 4; ++rg) {
                    int row = mi * 16 + lg * 4 + rg;
                    float v = acc[mi][ni][rg] + bb;
                    v = v > 0.f ? v : 0.f;
                    *(unsigned short*)(inA + ((row * 1024 + c * 2) ^ SWZ(row))) = f2b(v);
                }
            }
        }
    }
    __syncthreads();

    // GEMM2: out2[32][128]; wave covers cols [wv*32, +32)
    f32x4 acc2[2][2] = {};
    #pragma unroll
    for (int ks = 0; ks < 16; ++ks) {
        bf16x8 a2[2], b2f[2];
        #pragma unroll
        for (int mi = 0; mi < 2; ++mi) {
            int row = mi * 16 + lr;
            int off = (row * 1024 + ks * 64 + lg * 16) ^ SWZ(row);
            a2[mi] = *(const bf16x8*)(inA + off);
        }
        #pragma unroll
        for (int ni = 0; ni < 2; ++ni)
            b2f[ni] = *(const bf16x8*)(W2T + (size_t)(wv * 32 + ni * 16 + lr) * 512 + ks * 32 + lg * 8);
        #pragma unroll
        for (int mi = 0; mi < 2; ++mi)
            #pragma unroll
            for (int ni = 0; ni < 2; ++ni)
                acc2[mi][ni] = __builtin_amdgcn_mfma_f32_16x16x32_bf16(
                    a2[mi], b2f[ni], acc2[mi][ni], 0, 0, 0);
    }

    // epilogue: out = acc2 + b2 + h
    #pragma unroll
    for (int ni = 0; ni < 2; ++ni) {
        int col = wv * 32 + ni * 16 + lr;
        float bb2 = b2[col];
        #pragma unroll
        for (int mi = 0; mi < 2; ++mi) {
            #pragma unroll
            for (int rg = 0; rg < 4; ++rg) {
                int row = mi * 16 + lg * 4 + rg;
                int gr = r0 + row;
                if (gr < N_NODES) {
                    size_t idx = (size_t)gr * 128 + col;
                    out[idx] = acc2[mi][ni][rg] + bb2 + out[idx];
                }
            }
        }
    }
}

extern "C" void kernel_launch(void* const* d_in, const int* in_sizes, int n_in,
                              void* d_out, int out_size, void* d_ws, size_t ws_size,
                              hipStream_t stream) {
    const float* x     = (const float*)d_in[0];
    const float* Wfc   = (const float*)d_in[1];
    const float* a_l   = (const float*)d_in[2];
    const float* a_r   = (const float*)d_in[3];
    const float* gamma = (const float*)d_in[4];
    const float* beta  = (const float*)d_in[5];
    const float* W1    = (const float*)d_in[6];
    const float* b1    = (const float*)d_in[7];
    const float* W2    = (const float*)d_in[8];
    const float* b2    = (const float*)d_in[9];
    const int*   es    = (const int*)d_in[10];
    const int*   ed    = (const int*)d_in[11];
    float* out = (float*)d_out;

    bf16_t* W1T = (bf16_t*)d_ws;                      // 512*128
    bf16_t* W2T = W1T + 512 * 128;                    // 128*512
    bf16_t* WpT = W2T + 128 * 512;                    // 128*128
    unsigned short* zb = (unsigned short*)(WpT + 128 * 128);  // N*128 bf16
    float* el = (float*)(zb + (size_t)N_NODES * 128); // N*8
    float* er = el + N_NODES * 8;                     // N*8
    int* counts  = (int*)(er + N_NODES * 8);          // N
    int* csr_off = counts + N_NODES;                  // N+1
    int* cursor  = csr_off + N_NODES + 1;             // N+1
    int* csr_src = cursor + N_NODES + 1;              // E
    int* bsum    = csr_src + E_EDGES;                 // SCAN_BLOCKS
    int* boff    = bsum + 128;                        // 128

    k_zero<<<dim3((N_NODES + 255) / 256), dim3(256), 0, stream>>>(counts);
    k_count<<<dim3((E_EDGES + 255) / 256), dim3(256), 0, stream>>>(ed, counts);
    k_scan1<<<dim3(SCAN_BLOCKS), dim3(512), 0, stream>>>(counts, bsum);
    k_scan2<<<dim3(1), dim3(128), 0, stream>>>(bsum, boff);
    k_scan3<<<dim3(SCAN_BLOCKS), dim3(512), 0, stream>>>(counts, boff, csr_off, cursor);
    k_fill<<<dim3((E_EDGES + 255) / 256), dim3(256), 0, stream>>>(es, ed, cursor, csr_src);
    k_prep<<<dim3(256), dim3(256), 0, stream>>>(W1, W2, Wfc, W1T, W2T, WpT);
    k_proj<<<dim3((N_NODES + 63) / 64), dim3(512), 0, stream>>>(x, WpT, a_l, a_r, zb, el, er);
    k_node<<<dim3(N_NODES / 8), dim3(256), 0, stream>>>(csr_off, csr_src, el, er, zb, x, out);
    k_ffn<<<dim3((N_NODES + 31) / 32), dim3(256), 0, stream>>>(gamma, beta, W1T, b1, W2T, b2, out);
}